// Round 4
// baseline (831.405 us; speedup 1.0000x reference)
//
#include <hip/hip_runtime.h>
#include <stdint.h>

#define B_SZ 4096
#define K_SZ 4
#define D_SZ 1024
#define INV_T 14.285714285714286f   // 1/0.07
#define FP8_SCALE 16.0f             // input pre-scale; compensated by E8M0=123
#define E8M0_S 123                  // 2^(123-127) = 1/16 per operand

typedef __attribute__((ext_vector_type(8)))  int   i32x8_t;   // 32 fp8 bytes
typedef __attribute__((ext_vector_type(16))) float f32x16_t;  // 32x32 acc
typedef __attribute__((ext_vector_type(8)))  short bf16x8_t;
typedef __attribute__((ext_vector_type(4)))  float f32x4_t;
typedef unsigned short u16;

static __device__ __forceinline__ u16 f2bf(float f) {
    union { float f; uint32_t u; } v; v.f = f;
    return (u16)(v.u >> 16);
}

static __device__ __forceinline__ int pack_fp8(float4 a) {
    int p = __builtin_amdgcn_cvt_pk_fp8_f32(a.x * FP8_SCALE, a.y * FP8_SCALE, 0, false);
    return  __builtin_amdgcn_cvt_pk_fp8_f32(a.z * FP8_SCALE, a.w * FP8_SCALE, p, true);
}

// async global->LDS, 16 bytes/lane; dest must be wave-uniform base + lane*16
static __device__ __forceinline__ void gl_lds16(const void* g, void* l) {
    __builtin_amdgcn_global_load_lds(
        (const __attribute__((address_space(1))) void*)g,
        (__attribute__((address_space(3))) void*)l, 16, 0, 0);
}

// ===========================================================================
// MAIN PATH
// ===========================================================================

// ---------------------------------------------------------------------------
// Pass 1: convert + diagonal dots. Block b (0..4095) handles txt row b
// (loaded ONCE), img row b, oth rows 4b..4b+3, and all 5 diagonal dots.
// ---------------------------------------------------------------------------
__global__ __launch_bounds__(256) void convert_diag_f8(
    const float* __restrict__ img, const float* __restrict__ txt,
    const float* __restrict__ other,
    uint8_t* __restrict__ img_f8, uint8_t* __restrict__ txt_f8,
    uint8_t* __restrict__ oth_f8, float* __restrict__ partials)
{
    const int b = blockIdx.x;
    const int t = threadIdx.x;

    float4 ti = ((const float4*)(txt + (size_t)b * D_SZ))[t];
    ((int*)(txt_f8 + (size_t)b * D_SZ))[t] = pack_fp8(ti);

    float4 ii = ((const float4*)(img + (size_t)b * D_SZ))[t];
    ((int*)(img_f8 + (size_t)b * D_SZ))[t] = pack_fp8(ii);

    float d[5];
    d[0] = ii.x * ti.x + ii.y * ti.y + ii.z * ti.z + ii.w * ti.w;
#pragma unroll
    for (int k = 0; k < 4; k++) {
        float4 o = ((const float4*)(other + (size_t)(4 * b + k) * D_SZ))[t];
        ((int*)(oth_f8 + (size_t)(4 * b + k) * D_SZ))[t] = pack_fp8(o);
        d[1 + k] = o.x * ti.x + o.y * ti.y + o.z * ti.z + o.w * ti.w;
    }

    __shared__ float red[5][4];
    const int w = t >> 6, lane = t & 63;
#pragma unroll
    for (int i = 0; i < 5; i++) {
        float s = d[i];
#pragma unroll
        for (int dd = 1; dd < 64; dd <<= 1) s += __shfl_xor(s, dd);
        if (lane == 0) red[i][w] = s;
    }
    __syncthreads();
    if (t == 0) {
        partials[b] = (red[0][0] + red[0][1] + red[0][2] + red[0][3]) * INV_T;
#pragma unroll
        for (int k = 0; k < 4; k++)
            partials[B_SZ + 4 * b + k] =
                (red[1 + k][0] + red[1 + k][1] + red[1 + k][2] + red[1 + k][3]) * INV_T;
    }
}

// ---------------------------------------------------------------------------
// Pass 2: fused MX-fp8 GEMM+expsum. Tile 128(M=txt) x 256(N), BK=64.
// 4 waves; each wave: acc[4][2] of 32x32x64 MFMAs (A panels SHARED by all
// waves, wave w owns cols wn=w*64). LDS is stored in FRAGMENT ORDER:
//   A block (p,h), p=0..3, h=0..1: 1024 B; slot L (lane) holds
//     A[32p + (L&31)][k = 32*(L>>5) + 16h .. +16]
//   B blocks (q,h), q=0..7 at byte 8192 + (q*2+h)*1024, same per-slot map.
// => every fragment ds_read_b128 is base + lane*16: conflict-free.
// Staging slot s = c*256 + tid (c=0..5) is lane-linear in LDS, and the
// GLOBAL address is permuted per the map above (global_load_lds dest rule
// holds: per-wave uniform base + lane*16).
// Epilogue: n0<4096 (W = Q1^T): rowsum->cs1, colsum->rs1; else rowsum->rs2.
// ---------------------------------------------------------------------------
__global__ __launch_bounds__(256) void gemm_expsum_mx(
    const uint8_t* __restrict__ txt_f8, const uint8_t* __restrict__ img_f8,
    const uint8_t* __restrict__ oth_f8,
    float* __restrict__ rs1, float* __restrict__ cs1, float* __restrict__ rs2)
{
    __shared__ uint8_t lds[24576];   // A: [0,8192), B: [8192,24576)

    const int m0  = blockIdx.y * 128;           // txt rows
    const int n0  = blockIdx.x * 256;           // 0..20479 (boundary 4096 aligned)
    const bool q1 = (n0 < B_SZ);
    const uint8_t* Yb = q1 ? img_f8 + (size_t)n0 * D_SZ
                           : oth_f8 + (size_t)(n0 - B_SZ) * D_SZ;

    const int tid  = threadIdx.x;
    const int lane = tid & 63;
    const int w    = tid >> 6;
    const int wn   = w * 64;
    const int l31  = lane & 31;
    const int kh   = lane >> 5;

    // precompute the 6 staging global pointers (slot s = c*256 + tid)
    const uint8_t* gsrc[6];
#pragma unroll
    for (int c = 0; c < 6; c++) {
        const int s = c * 256 + tid;
        if (c < 2) {            // A slots 0..511
            const int pp = s >> 7, h = (s >> 6) & 1, L = s & 63;
            gsrc[c] = txt_f8 + (size_t)(m0 + 32 * pp + (L & 31)) * D_SZ
                             + 32 * (L >> 5) + 16 * h;
        } else {                // B slots 0..1023
            const int s2 = s - 512;
            const int qq = s2 >> 7, h = (s2 >> 6) & 1, L = s2 & 63;
            gsrc[c] = Yb + (size_t)(32 * qq + (L & 31)) * D_SZ
                         + 32 * (L >> 5) + 16 * h;
        }
    }

    f32x16_t acc[4][2];
#pragma unroll
    for (int i = 0; i < 4; i++)
#pragma unroll
        for (int j = 0; j < 2; j++)
#pragma unroll
            for (int r = 0; r < 16; r++) acc[i][j][r] = 0.f;

    for (int k0 = 0; k0 < D_SZ; k0 += 64) {
#pragma unroll
        for (int c = 0; c < 6; c++)
            gl_lds16(gsrc[c] + k0, lds + ((size_t)(c * 256 + tid)) * 16);
        __syncthreads();

        i32x8_t af[4], bfr[2];
#pragma unroll
        for (int mt = 0; mt < 4; mt++) {
            int4 lo = *(const int4*)(lds + mt * 2048 + lane * 16);
            int4 hi = *(const int4*)(lds + mt * 2048 + 1024 + lane * 16);
            af[mt][0] = lo.x; af[mt][1] = lo.y; af[mt][2] = lo.z; af[mt][3] = lo.w;
            af[mt][4] = hi.x; af[mt][5] = hi.y; af[mt][6] = hi.z; af[mt][7] = hi.w;
        }
#pragma unroll
        for (int nt = 0; nt < 2; nt++) {
            const int qq = 2 * w + nt;
            int4 lo = *(const int4*)(lds + 8192 + qq * 2048 + lane * 16);
            int4 hi = *(const int4*)(lds + 8192 + qq * 2048 + 1024 + lane * 16);
            bfr[nt][0] = lo.x; bfr[nt][1] = lo.y; bfr[nt][2] = lo.z; bfr[nt][3] = lo.w;
            bfr[nt][4] = hi.x; bfr[nt][5] = hi.y; bfr[nt][6] = hi.z; bfr[nt][7] = hi.w;
        }

#pragma unroll
        for (int mt = 0; mt < 4; mt++)
#pragma unroll
            for (int nt = 0; nt < 2; nt++)
                acc[mt][nt] = __builtin_amdgcn_mfma_scale_f32_32x32x64_f8f6f4(
                    af[mt], bfr[nt], acc[mt][nt], 0, 0, 0, E8M0_S, 0, E8M0_S);
        __syncthreads();
    }

    // Epilogue. 32x32 C/D: col = l31, row = (r&3) + 8*(r>>2) + 4*kh.
    float* rtgt = q1 ? cs1 : rs2;
    float colp[2] = {0.f, 0.f};
#pragma unroll
    for (int mt = 0; mt < 4; mt++) {
        float rowp[16];
#pragma unroll
        for (int r = 0; r < 16; r++) rowp[r] = 0.f;
#pragma unroll
        for (int nt = 0; nt < 2; nt++)
#pragma unroll
            for (int r = 0; r < 16; r++) {
                float e = __expf(acc[mt][nt][r] * INV_T);
                rowp[r] += e;
                colp[nt] += e;
            }
#pragma unroll
        for (int r = 0; r < 16; r++) {
            float v = rowp[r];
            v += __shfl_xor(v, 1);
            v += __shfl_xor(v, 2);
            v += __shfl_xor(v, 4);
            v += __shfl_xor(v, 8);
            v += __shfl_xor(v, 16);
            if (l31 == 0) {
                const int row = m0 + 32 * mt + (r & 3) + 8 * (r >> 2) + 4 * kh;
                atomicAdd(&rtgt[row], v);
            }
        }
    }
    if (q1) {
#pragma unroll
        for (int nt = 0; nt < 2; nt++) {
            float c = colp[nt];
            c += __shfl_xor(c, 32);
            if (lane < 32)
                atomicAdd(&rs1[n0 + wn + 32 * nt + l31], c);
        }
    }
}

// ---------------------------------------------------------------------------
// Finalize: logs of expsums + 20480 diagonal partials.
// ---------------------------------------------------------------------------
__global__ __launch_bounds__(256) void finalize_part(
    const float* __restrict__ rs1, const float* __restrict__ cs1,
    const float* __restrict__ rs2, const float* __restrict__ partials,
    float* __restrict__ out)
{
    float s1 = 0.f, s2 = 0.f, s3 = 0.f, pd = 0.f, pm = 0.f;
    for (int i = threadIdx.x; i < B_SZ; i += 256) {
        s1 += __logf(rs1[i]);
        s2 += __logf(cs1[i]);
        s3 += __logf(rs2[i]);
        pd += partials[i];
    }
    for (int i = threadIdx.x; i < B_SZ * K_SZ; i += 256)
        pm += partials[B_SZ + i];
#pragma unroll
    for (int d = 1; d < 64; d <<= 1) {
        s1 += __shfl_xor(s1, d); s2 += __shfl_xor(s2, d);
        s3 += __shfl_xor(s3, d); pd += __shfl_xor(pd, d);
        pm += __shfl_xor(pm, d);
    }
    __shared__ float red[5][4];
    const int w = threadIdx.x >> 6, lane = threadIdx.x & 63;
    if (lane == 0) {
        red[0][w] = s1; red[1][w] = s2; red[2][w] = s3;
        red[3][w] = pd; red[4][w] = pm;
    }
    __syncthreads();
    if (threadIdx.x == 0) {
        float S1 = red[0][0] + red[0][1] + red[0][2] + red[0][3];
        float S2 = red[1][0] + red[1][1] + red[1][2] + red[1][3];
        float S3 = red[2][0] + red[2][1] + red[2][2] + red[2][3];
        float DS = red[3][0] + red[3][1] + red[3][2] + red[3][3];
        float MS = red[4][0] + red[4][1] + red[4][2] + red[4][3];
        const float invB = 1.0f / (float)B_SZ;
        out[0] = 0.5f * (S1 + S2) * invB - DS * invB
               + 0.5f * (S3 * invB - MS / ((float)B_SZ * K_SZ));
    }
}

// ===========================================================================
// FALLBACK PATH (fp32->bf16 in-kernel, no workspace) ------------------------
// ===========================================================================
template <bool COLSUM>
__global__ __launch_bounds__(256) void gemm_expsum(
    const float* __restrict__ X, const float* __restrict__ Y,
    float* __restrict__ rowsum, float* __restrict__ colsum)
{
    __shared__ u16 As[128][32];
    __shared__ u16 Bs[128][32];
    const int m0 = blockIdx.y * 128, n0 = blockIdx.x * 128;
    const int tid = threadIdx.x, lane = tid & 63, w = tid >> 6;
    const int wm = (w & 1) * 64, wn = (w >> 1) * 64;
    const int lr = lane & 15, q = lane >> 4;
    f32x4_t acc[4][4];
#pragma unroll
    for (int i = 0; i < 4; i++)
#pragma unroll
        for (int j = 0; j < 4; j++) acc[i][j] = (f32x4_t){0.f, 0.f, 0.f, 0.f};
    const int kv = (tid & 7) * 4, r0 = tid >> 3;
    const float* xb = X + (size_t)(m0 + r0) * D_SZ + kv;
    const float* yb = Y + (size_t)(n0 + r0) * D_SZ + kv;
    for (int k0 = 0; k0 < D_SZ; k0 += 32) {
#pragma unroll
        for (int i = 0; i < 4; i++) {
            float4 a = *(const float4*)(xb + (size_t)(32 * i) * D_SZ + k0);
            float4 b = *(const float4*)(yb + (size_t)(32 * i) * D_SZ + k0);
            ushort4 ua, ub;
            ua.x = f2bf(a.x); ua.y = f2bf(a.y); ua.z = f2bf(a.z); ua.w = f2bf(a.w);
            ub.x = f2bf(b.x); ub.y = f2bf(b.y); ub.z = f2bf(b.z); ub.w = f2bf(b.w);
            *(ushort4*)&As[r0 + 32 * i][kv] = ua;
            *(ushort4*)&Bs[r0 + 32 * i][kv] = ub;
        }
        __syncthreads();
        bf16x8_t af[4], bfr[4];
#pragma unroll
        for (int mt = 0; mt < 4; mt++)
            af[mt] = *(const bf16x8_t*)&As[wm + 16 * mt + lr][8 * q];
#pragma unroll
        for (int nt = 0; nt < 4; nt++)
            bfr[nt] = *(const bf16x8_t*)&Bs[wn + 16 * nt + lr][8 * q];
#pragma unroll
        for (int mt = 0; mt < 4; mt++)
#pragma unroll
            for (int nt = 0; nt < 4; nt++)
                acc[mt][nt] = __builtin_amdgcn_mfma_f32_16x16x32_bf16(
                    af[mt], bfr[nt], acc[mt][nt], 0, 0, 0);
        __syncthreads();
    }
    float rowp[4][4];
#pragma unroll
    for (int mt = 0; mt < 4; mt++)
#pragma unroll
        for (int r = 0; r < 4; r++) rowp[mt][r] = 0.f;
#pragma unroll
    for (int nt = 0; nt < 4; nt++) {
        float colp = 0.f;
#pragma unroll
        for (int mt = 0; mt < 4; mt++)
#pragma unroll
            for (int r = 0; r < 4; r++) {
                float e = __expf(acc[mt][nt][r] * INV_T);
                colp += e; rowp[mt][r] += e;
            }
        if (COLSUM) {
            colp += __shfl_xor(colp, 16);
            colp += __shfl_xor(colp, 32);
            if (q == 0) atomicAdd(&colsum[n0 + wn + 16 * nt + lr], colp);
        }
    }
#pragma unroll
    for (int mt = 0; mt < 4; mt++)
#pragma unroll
        for (int r = 0; r < 4; r++) {
            float rp = rowp[mt][r];
            rp += __shfl_xor(rp, 1); rp += __shfl_xor(rp, 2);
            rp += __shfl_xor(rp, 4); rp += __shfl_xor(rp, 8);
            if (lr == 0) atomicAdd(&rowsum[m0 + wm + 16 * mt + 4 * q + r], rp);
        }
}

__global__ __launch_bounds__(256) void diag_kernel(
    const float* __restrict__ img, const float* __restrict__ txt,
    const float* __restrict__ other, float* __restrict__ dm)
{
    const int gw = blockIdx.x * 4 + (threadIdx.x >> 6);
    const int lane = threadIdx.x & 63;
    const float *pa, *pb; float* target;
    if (gw < B_SZ) {
        pa = img + (size_t)gw * D_SZ; pb = txt + (size_t)gw * D_SZ; target = dm;
    } else {
        const int g2 = gw - B_SZ;
        pa = other + (size_t)g2 * D_SZ; pb = txt + (size_t)(g2 >> 2) * D_SZ;
        target = dm + 1;
    }
    float s = 0.f;
#pragma unroll
    for (int j = 0; j < 4; j++) {
        float4 a = *(const float4*)(pa + 4 * (lane + 64 * j));
        float4 b = *(const float4*)(pb + 4 * (lane + 64 * j));
        s += a.x * b.x + a.y * b.y + a.z * b.z + a.w * b.w;
    }
#pragma unroll
    for (int d = 1; d < 64; d <<= 1) s += __shfl_xor(s, d);
    if (lane == 0) atomicAdd(target, s * INV_T);
}

__global__ __launch_bounds__(256) void finalize_atomic(
    const float* __restrict__ rs1, const float* __restrict__ cs1,
    const float* __restrict__ rs2, const float* __restrict__ dm,
    float* __restrict__ out)
{
    float s1 = 0.f, s2 = 0.f, s3 = 0.f;
    for (int i = threadIdx.x; i < B_SZ; i += 256) {
        s1 += __logf(rs1[i]); s2 += __logf(cs1[i]); s3 += __logf(rs2[i]);
    }
#pragma unroll
    for (int d = 1; d < 64; d <<= 1) {
        s1 += __shfl_xor(s1, d); s2 += __shfl_xor(s2, d); s3 += __shfl_xor(s3, d);
    }
    __shared__ float red[3][4];
    const int w = threadIdx.x >> 6, lane = threadIdx.x & 63;
    if (lane == 0) { red[0][w] = s1; red[1][w] = s2; red[2][w] = s3; }
    __syncthreads();
    if (threadIdx.x == 0) {
        float S1 = red[0][0] + red[0][1] + red[0][2] + red[0][3];
        float S2 = red[1][0] + red[1][1] + red[1][2] + red[1][3];
        float S3 = red[2][0] + red[2][1] + red[2][2] + red[2][3];
        const float invB = 1.0f / (float)B_SZ;
        out[0] = 0.5f * (S1 + S2) * invB - dm[0] * invB
               + 0.5f * (S3 * invB - dm[1] / ((float)B_SZ * K_SZ));
    }
}

// ===========================================================================
extern "C" void kernel_launch(void* const* d_in, const int* in_sizes, int n_in,
                              void* d_out, int out_size, void* d_ws, size_t ws_size,
                              hipStream_t stream) {
    const float* img   = (const float*)d_in[0];
    const float* txt   = (const float*)d_in[1];
    const float* other = (const float*)d_in[2];
    float* out = (float*)d_out;
    float* ws  = (float*)d_ws;

    float* rs1      = ws;                    // [4096]
    float* cs1      = ws + B_SZ;             // [4096]
    float* rs2      = ws + 2 * B_SZ;         // [4096]
    float* partials = ws + 3 * B_SZ;         // [20480] (main)
    float* dm       = ws + 3 * B_SZ;         // [2]     (fallback)

    const size_t hdr_floats = 3 * B_SZ + B_SZ + B_SZ * K_SZ;              // 32768
    const size_t f8_bytes   = (size_t)(2 * B_SZ + B_SZ * K_SZ) * D_SZ;    // 24 MB
    const size_t need = hdr_floats * sizeof(float) + f8_bytes;

    if (ws_size >= need) {
        uint8_t* img_f8 = (uint8_t*)(ws + hdr_floats);
        uint8_t* txt_f8 = img_f8 + (size_t)B_SZ * D_SZ;
        uint8_t* oth_f8 = txt_f8 + (size_t)B_SZ * D_SZ;

        hipMemsetAsync(d_ws, 0, 3 * B_SZ * sizeof(float), stream);
        hipLaunchKernelGGL(convert_diag_f8, dim3(B_SZ), dim3(256),
                           0, stream, img, txt, other, img_f8, txt_f8, oth_f8,
                           partials);
        // fused W = txt . [img ; oth]^T : tiles 256 N x 128 M -> 80 x 32
        hipLaunchKernelGGL(gemm_expsum_mx,
                           dim3((B_SZ + B_SZ * K_SZ) / 256, B_SZ / 128), dim3(256),
                           0, stream, txt_f8, img_f8, oth_f8, rs1, cs1, rs2);
        hipLaunchKernelGGL(finalize_part, dim3(1), dim3(256), 0, stream,
                           rs1, cs1, rs2, partials, out);
    } else {
        hipMemsetAsync(d_ws, 0, (3 * B_SZ + 2) * sizeof(float), stream);
        hipLaunchKernelGGL((gemm_expsum<true>), dim3(B_SZ / 128, B_SZ / 128),
                           dim3(256), 0, stream, img, txt, rs1, cs1);
        hipLaunchKernelGGL((gemm_expsum<false>),
                           dim3(B_SZ * K_SZ / 128, B_SZ / 128), dim3(256), 0,
                           stream, txt, other, rs2, nullptr);
        hipLaunchKernelGGL(diag_kernel, dim3((B_SZ + B_SZ * K_SZ) / 4),
                           dim3(256), 0, stream, img, txt, other, dm);
        hipLaunchKernelGGL(finalize_atomic, dim3(1), dim3(256), 0, stream,
                           rs1, cs1, rs2, dm, out);
    }
}

// Round 5
// 681.115 us; speedup vs baseline: 1.2207x; 1.2207x over previous
//
#include <hip/hip_runtime.h>
#include <stdint.h>

#define B_SZ 4096
#define K_SZ 4
#define D_SZ 1024
#define INV_T 14.285714285714286f   // 1/0.07
#define FP8_SCALE 16.0f             // input pre-scale; compensated by E8M0=123
#define E8M0_S 123                  // 2^(123-127) = 1/16 per operand

typedef __attribute__((ext_vector_type(8)))  int   i32x8_t;   // 32 fp8 bytes
typedef __attribute__((ext_vector_type(16))) float f32x16_t;  // 32x32 acc
typedef __attribute__((ext_vector_type(8)))  short bf16x8_t;
typedef __attribute__((ext_vector_type(4)))  float f32x4_t;
typedef unsigned short u16;

static __device__ __forceinline__ u16 f2bf(float f) {
    union { float f; uint32_t u; } v; v.f = f;
    return (u16)(v.u >> 16);
}

static __device__ __forceinline__ int pack_fp8(float4 a) {
    int p = __builtin_amdgcn_cvt_pk_fp8_f32(a.x * FP8_SCALE, a.y * FP8_SCALE, 0, false);
    return  __builtin_amdgcn_cvt_pk_fp8_f32(a.z * FP8_SCALE, a.w * FP8_SCALE, p, true);
}

// async global->LDS, 16 bytes/lane; dest must be wave-uniform base + lane*16
static __device__ __forceinline__ void gl_lds16(const void* g, void* l) {
    __builtin_amdgcn_global_load_lds(
        (const __attribute__((address_space(1))) void*)g,
        (__attribute__((address_space(3))) void*)l, 16, 0, 0);
}

// ===========================================================================
// MAIN PATH
// ===========================================================================

// ---------------------------------------------------------------------------
// Pass 1: convert + diagonal dots. Block b (0..4095) handles txt row b
// (loaded ONCE), img row b, oth rows 4b..4b+3, and all 5 diagonal dots.
// ---------------------------------------------------------------------------
__global__ __launch_bounds__(256) void convert_diag_f8(
    const float* __restrict__ img, const float* __restrict__ txt,
    const float* __restrict__ other,
    uint8_t* __restrict__ img_f8, uint8_t* __restrict__ txt_f8,
    uint8_t* __restrict__ oth_f8, float* __restrict__ partials)
{
    const int b = blockIdx.x;
    const int t = threadIdx.x;

    float4 ti = ((const float4*)(txt + (size_t)b * D_SZ))[t];
    ((int*)(txt_f8 + (size_t)b * D_SZ))[t] = pack_fp8(ti);

    float4 ii = ((const float4*)(img + (size_t)b * D_SZ))[t];
    ((int*)(img_f8 + (size_t)b * D_SZ))[t] = pack_fp8(ii);

    float d[5];
    d[0] = ii.x * ti.x + ii.y * ti.y + ii.z * ti.z + ii.w * ti.w;
#pragma unroll
    for (int k = 0; k < 4; k++) {
        float4 o = ((const float4*)(other + (size_t)(4 * b + k) * D_SZ))[t];
        ((int*)(oth_f8 + (size_t)(4 * b + k) * D_SZ))[t] = pack_fp8(o);
        d[1 + k] = o.x * ti.x + o.y * ti.y + o.z * ti.z + o.w * ti.w;
    }

    __shared__ float red[5][4];
    const int w = t >> 6, lane = t & 63;
#pragma unroll
    for (int i = 0; i < 5; i++) {
        float s = d[i];
#pragma unroll
        for (int dd = 1; dd < 64; dd <<= 1) s += __shfl_xor(s, dd);
        if (lane == 0) red[i][w] = s;
    }
    __syncthreads();
    if (t == 0) {
        partials[b] = (red[0][0] + red[0][1] + red[0][2] + red[0][3]) * INV_T;
#pragma unroll
        for (int k = 0; k < 4; k++)
            partials[B_SZ + 4 * b + k] =
                (red[1 + k][0] + red[1 + k][1] + red[1 + k][2] + red[1 + k][3]) * INV_T;
    }
}

// ---------------------------------------------------------------------------
// Pass 2: fused MX-fp8 GEMM+expsum. Tile 128(M=txt) x 128(N), BK=64.
// 4 waves, each a 64x64 quadrant = acc[2][2] of 32x32x64 MFMAs (64 AGPRs --
// round 4's 4x2 shape spilled at 128 AGPRs; launch_bounds(256,2) caps 256).
// LDS stored in FRAGMENT ORDER (round-4-verified, SQ_LDS_BANK_CONFLICT=0):
//   tensor block (p,h), p=0..3 panels of 32 rows, h=0..1 k-halves: 1024 B
//   at (p*2+h)*1024; slot L holds row 32p+(L&31), k=32*(L>>5)+16h.
// => every fragment ds_read_b128 is base + lane*16: conflict-free, and the
// staging side is lane-linear so the global_load_lds dest rule holds.
// Epilogue: n0<4096 (W = Q1^T): rowsum->cs1, colsum->rs1; else rowsum->rs2.
// ---------------------------------------------------------------------------
__global__ __launch_bounds__(256, 2) void gemm_expsum_mx(
    const uint8_t* __restrict__ txt_f8, const uint8_t* __restrict__ img_f8,
    const uint8_t* __restrict__ oth_f8,
    float* __restrict__ rs1, float* __restrict__ cs1, float* __restrict__ rs2)
{
    __shared__ uint8_t lds[16384];   // A: [0,8192), B: [8192,16384)

    const int m0  = blockIdx.y * 128;           // txt rows
    const int n0  = blockIdx.x * 128;           // 0..20479
    const bool q1 = (n0 < B_SZ);
    const uint8_t* Yb = q1 ? img_f8 + (size_t)n0 * D_SZ
                           : oth_f8 + (size_t)(n0 - B_SZ) * D_SZ;

    const int tid  = threadIdx.x;
    const int lane = tid & 63;
    const int w    = tid >> 6;
    const int wm   = (w & 1) * 64;
    const int wn   = (w >> 1) * 64;
    const int l31  = lane & 31;
    const int kh   = lane >> 5;

    // staging: 4 slots/thread; slot s = (c&1)*256 + tid within each tensor
    const uint8_t* gsrc[4];
#pragma unroll
    for (int c = 0; c < 4; c++) {
        const int s  = (c & 1) * 256 + tid;          // 0..511
        const int pp = s >> 7, h = (s >> 6) & 1, L = s & 63;
        const int row = 32 * pp + (L & 31);
        const int kk  = 32 * (L >> 5) + 16 * h;
        gsrc[c] = (c < 2 ? txt_f8 + (size_t)(m0 + row) * D_SZ
                         : Yb + (size_t)row * D_SZ) + kk;
    }

    f32x16_t acc[2][2];
#pragma unroll
    for (int i = 0; i < 2; i++)
#pragma unroll
        for (int j = 0; j < 2; j++)
#pragma unroll
            for (int r = 0; r < 16; r++) acc[i][j][r] = 0.f;

    for (int k0 = 0; k0 < D_SZ; k0 += 64) {
#pragma unroll
        for (int c = 0; c < 4; c++)
            gl_lds16(gsrc[c] + k0,
                     lds + (c < 2 ? 0 : 8192) + ((c & 1) * 256 + tid) * 16);
        __syncthreads();

        i32x8_t af[2], bfr[2];
#pragma unroll
        for (int mt = 0; mt < 2; mt++) {
            const int pp = 2 * (w & 1) + mt;
            int4 lo = *(const int4*)(lds + pp * 2048 + lane * 16);
            int4 hi = *(const int4*)(lds + pp * 2048 + 1024 + lane * 16);
            af[mt][0] = lo.x; af[mt][1] = lo.y; af[mt][2] = lo.z; af[mt][3] = lo.w;
            af[mt][4] = hi.x; af[mt][5] = hi.y; af[mt][6] = hi.z; af[mt][7] = hi.w;
        }
#pragma unroll
        for (int nt = 0; nt < 2; nt++) {
            const int qq = 2 * (w >> 1) + nt;
            int4 lo = *(const int4*)(lds + 8192 + qq * 2048 + lane * 16);
            int4 hi = *(const int4*)(lds + 8192 + qq * 2048 + 1024 + lane * 16);
            bfr[nt][0] = lo.x; bfr[nt][1] = lo.y; bfr[nt][2] = lo.z; bfr[nt][3] = lo.w;
            bfr[nt][4] = hi.x; bfr[nt][5] = hi.y; bfr[nt][6] = hi.z; bfr[nt][7] = hi.w;
        }

#pragma unroll
        for (int mt = 0; mt < 2; mt++)
#pragma unroll
            for (int nt = 0; nt < 2; nt++)
                acc[mt][nt] = __builtin_amdgcn_mfma_scale_f32_32x32x64_f8f6f4(
                    af[mt], bfr[nt], acc[mt][nt], 0, 0, 0, E8M0_S, 0, E8M0_S);
        __syncthreads();
    }

    // Epilogue. 32x32 C/D: col = l31, row = (r&3) + 8*(r>>2) + 4*kh.
    float* rtgt = q1 ? cs1 : rs2;
    float colp[2] = {0.f, 0.f};
#pragma unroll
    for (int mt = 0; mt < 2; mt++) {
        float rowp[16];
#pragma unroll
        for (int r = 0; r < 16; r++) rowp[r] = 0.f;
#pragma unroll
        for (int nt = 0; nt < 2; nt++)
#pragma unroll
            for (int r = 0; r < 16; r++) {
                float e = __expf(acc[mt][nt][r] * INV_T);
                rowp[r] += e;
                colp[nt] += e;
            }
#pragma unroll
        for (int r = 0; r < 16; r++) {
            float v = rowp[r];
            v += __shfl_xor(v, 1);
            v += __shfl_xor(v, 2);
            v += __shfl_xor(v, 4);
            v += __shfl_xor(v, 8);
            v += __shfl_xor(v, 16);
            if (l31 == 0) {
                const int row = m0 + wm + 32 * mt + (r & 3) + 8 * (r >> 2) + 4 * kh;
                atomicAdd(&rtgt[row], v);
            }
        }
    }
    if (q1) {
#pragma unroll
        for (int nt = 0; nt < 2; nt++) {
            float c = colp[nt];
            c += __shfl_xor(c, 32);
            if (lane < 32)
                atomicAdd(&rs1[n0 + wn + 32 * nt + l31], c);
        }
    }
}

// ---------------------------------------------------------------------------
// Finalize: logs of expsums + 20480 diagonal partials.
// ---------------------------------------------------------------------------
__global__ __launch_bounds__(256) void finalize_part(
    const float* __restrict__ rs1, const float* __restrict__ cs1,
    const float* __restrict__ rs2, const float* __restrict__ partials,
    float* __restrict__ out)
{
    float s1 = 0.f, s2 = 0.f, s3 = 0.f, pd = 0.f, pm = 0.f;
    for (int i = threadIdx.x; i < B_SZ; i += 256) {
        s1 += __logf(rs1[i]);
        s2 += __logf(cs1[i]);
        s3 += __logf(rs2[i]);
        pd += partials[i];
    }
    for (int i = threadIdx.x; i < B_SZ * K_SZ; i += 256)
        pm += partials[B_SZ + i];
#pragma unroll
    for (int d = 1; d < 64; d <<= 1) {
        s1 += __shfl_xor(s1, d); s2 += __shfl_xor(s2, d);
        s3 += __shfl_xor(s3, d); pd += __shfl_xor(pd, d);
        pm += __shfl_xor(pm, d);
    }
    __shared__ float red[5][4];
    const int w = threadIdx.x >> 6, lane = threadIdx.x & 63;
    if (lane == 0) {
        red[0][w] = s1; red[1][w] = s2; red[2][w] = s3;
        red[3][w] = pd; red[4][w] = pm;
    }
    __syncthreads();
    if (threadIdx.x == 0) {
        float S1 = red[0][0] + red[0][1] + red[0][2] + red[0][3];
        float S2 = red[1][0] + red[1][1] + red[1][2] + red[1][3];
        float S3 = red[2][0] + red[2][1] + red[2][2] + red[2][3];
        float DS = red[3][0] + red[3][1] + red[3][2] + red[3][3];
        float MS = red[4][0] + red[4][1] + red[4][2] + red[4][3];
        const float invB = 1.0f / (float)B_SZ;
        out[0] = 0.5f * (S1 + S2) * invB - DS * invB
               + 0.5f * (S3 * invB - MS / ((float)B_SZ * K_SZ));
    }
}

// ===========================================================================
// FALLBACK PATH (fp32->bf16 in-kernel, no workspace) ------------------------
// ===========================================================================
template <bool COLSUM>
__global__ __launch_bounds__(256) void gemm_expsum(
    const float* __restrict__ X, const float* __restrict__ Y,
    float* __restrict__ rowsum, float* __restrict__ colsum)
{
    __shared__ u16 As[128][32];
    __shared__ u16 Bs[128][32];
    const int m0 = blockIdx.y * 128, n0 = blockIdx.x * 128;
    const int tid = threadIdx.x, lane = tid & 63, w = tid >> 6;
    const int wm = (w & 1) * 64, wn = (w >> 1) * 64;
    const int lr = lane & 15, q = lane >> 4;
    f32x4_t acc[4][4];
#pragma unroll
    for (int i = 0; i < 4; i++)
#pragma unroll
        for (int j = 0; j < 4; j++) acc[i][j] = (f32x4_t){0.f, 0.f, 0.f, 0.f};
    const int kv = (tid & 7) * 4, r0 = tid >> 3;
    const float* xb = X + (size_t)(m0 + r0) * D_SZ + kv;
    const float* yb = Y + (size_t)(n0 + r0) * D_SZ + kv;
    for (int k0 = 0; k0 < D_SZ; k0 += 32) {
#pragma unroll
        for (int i = 0; i < 4; i++) {
            float4 a = *(const float4*)(xb + (size_t)(32 * i) * D_SZ + k0);
            float4 b = *(const float4*)(yb + (size_t)(32 * i) * D_SZ + k0);
            ushort4 ua, ub;
            ua.x = f2bf(a.x); ua.y = f2bf(a.y); ua.z = f2bf(a.z); ua.w = f2bf(a.w);
            ub.x = f2bf(b.x); ub.y = f2bf(b.y); ub.z = f2bf(b.z); ub.w = f2bf(b.w);
            *(ushort4*)&As[r0 + 32 * i][kv] = ua;
            *(ushort4*)&Bs[r0 + 32 * i][kv] = ub;
        }
        __syncthreads();
        bf16x8_t af[4], bfr[4];
#pragma unroll
        for (int mt = 0; mt < 4; mt++)
            af[mt] = *(const bf16x8_t*)&As[wm + 16 * mt + lr][8 * q];
#pragma unroll
        for (int nt = 0; nt < 4; nt++)
            bfr[nt] = *(const bf16x8_t*)&Bs[wn + 16 * nt + lr][8 * q];
#pragma unroll
        for (int mt = 0; mt < 4; mt++)
#pragma unroll
            for (int nt = 0; nt < 4; nt++)
                acc[mt][nt] = __builtin_amdgcn_mfma_f32_16x16x32_bf16(
                    af[mt], bfr[nt], acc[mt][nt], 0, 0, 0);
        __syncthreads();
    }
    float rowp[4][4];
#pragma unroll
    for (int mt = 0; mt < 4; mt++)
#pragma unroll
        for (int r = 0; r < 4; r++) rowp[mt][r] = 0.f;
#pragma unroll
    for (int nt = 0; nt < 4; nt++) {
        float colp = 0.f;
#pragma unroll
        for (int mt = 0; mt < 4; mt++)
#pragma unroll
            for (int r = 0; r < 4; r++) {
                float e = __expf(acc[mt][nt][r] * INV_T);
                colp += e; rowp[mt][r] += e;
            }
        if (COLSUM) {
            colp += __shfl_xor(colp, 16);
            colp += __shfl_xor(colp, 32);
            if (q == 0) atomicAdd(&colsum[n0 + wn + 16 * nt + lr], colp);
        }
    }
#pragma unroll
    for (int mt = 0; mt < 4; mt++)
#pragma unroll
        for (int r = 0; r < 4; r++) {
            float rp = rowp[mt][r];
            rp += __shfl_xor(rp, 1); rp += __shfl_xor(rp, 2);
            rp += __shfl_xor(rp, 4); rp += __shfl_xor(rp, 8);
            if (lr == 0) atomicAdd(&rowsum[m0 + wm + 16 * mt + 4 * q + r], rp);
        }
}

__global__ __launch_bounds__(256) void diag_kernel(
    const float* __restrict__ img, const float* __restrict__ txt,
    const float* __restrict__ other, float* __restrict__ dm)
{
    const int gw = blockIdx.x * 4 + (threadIdx.x >> 6);
    const int lane = threadIdx.x & 63;
    const float *pa, *pb; float* target;
    if (gw < B_SZ) {
        pa = img + (size_t)gw * D_SZ; pb = txt + (size_t)gw * D_SZ; target = dm;
    } else {
        const int g2 = gw - B_SZ;
        pa = other + (size_t)g2 * D_SZ; pb = txt + (size_t)(g2 >> 2) * D_SZ;
        target = dm + 1;
    }
    float s = 0.f;
#pragma unroll
    for (int j = 0; j < 4; j++) {
        float4 a = *(const float4*)(pa + 4 * (lane + 64 * j));
        float4 b = *(const float4*)(pb + 4 * (lane + 64 * j));
        s += a.x * b.x + a.y * b.y + a.z * b.z + a.w * b.w;
    }
#pragma unroll
    for (int d = 1; d < 64; d <<= 1) s += __shfl_xor(s, d);
    if (lane == 0) atomicAdd(target, s * INV_T);
}

__global__ __launch_bounds__(256) void finalize_atomic(
    const float* __restrict__ rs1, const float* __restrict__ cs1,
    const float* __restrict__ rs2, const float* __restrict__ dm,
    float* __restrict__ out)
{
    float s1 = 0.f, s2 = 0.f, s3 = 0.f;
    for (int i = threadIdx.x; i < B_SZ; i += 256) {
        s1 += __logf(rs1[i]); s2 += __logf(cs1[i]); s3 += __logf(rs2[i]);
    }
#pragma unroll
    for (int d = 1; d < 64; d <<= 1) {
        s1 += __shfl_xor(s1, d); s2 += __shfl_xor(s2, d); s3 += __shfl_xor(s3, d);
    }
    __shared__ float red[3][4];
    const int w = threadIdx.x >> 6, lane = threadIdx.x & 63;
    if (lane == 0) { red[0][w] = s1; red[1][w] = s2; red[2][w] = s3; }
    __syncthreads();
    if (threadIdx.x == 0) {
        float S1 = red[0][0] + red[0][1] + red[0][2] + red[0][3];
        float S2 = red[1][0] + red[1][1] + red[1][2] + red[1][3];
        float S3 = red[2][0] + red[2][1] + red[2][2] + red[2][3];
        const float invB = 1.0f / (float)B_SZ;
        out[0] = 0.5f * (S1 + S2) * invB - dm[0] * invB
               + 0.5f * (S3 * invB - dm[1] / ((float)B_SZ * K_SZ));
    }
}

// ===========================================================================
extern "C" void kernel_launch(void* const* d_in, const int* in_sizes, int n_in,
                              void* d_out, int out_size, void* d_ws, size_t ws_size,
                              hipStream_t stream) {
    const float* img   = (const float*)d_in[0];
    const float* txt   = (const float*)d_in[1];
    const float* other = (const float*)d_in[2];
    float* out = (float*)d_out;
    float* ws  = (float*)d_ws;

    float* rs1      = ws;                    // [4096]
    float* cs1      = ws + B_SZ;             // [4096]
    float* rs2      = ws + 2 * B_SZ;         // [4096]
    float* partials = ws + 3 * B_SZ;         // [20480] (main)
    float* dm       = ws + 3 * B_SZ;         // [2]     (fallback)

    const size_t hdr_floats = 3 * B_SZ + B_SZ + B_SZ * K_SZ;              // 32768
    const size_t f8_bytes   = (size_t)(2 * B_SZ + B_SZ * K_SZ) * D_SZ;    // 24 MB
    const size_t need = hdr_floats * sizeof(float) + f8_bytes;

    if (ws_size >= need) {
        uint8_t* img_f8 = (uint8_t*)(ws + hdr_floats);
        uint8_t* txt_f8 = img_f8 + (size_t)B_SZ * D_SZ;
        uint8_t* oth_f8 = txt_f8 + (size_t)B_SZ * D_SZ;

        hipMemsetAsync(d_ws, 0, 3 * B_SZ * sizeof(float), stream);
        hipLaunchKernelGGL(convert_diag_f8, dim3(B_SZ), dim3(256),
                           0, stream, img, txt, other, img_f8, txt_f8, oth_f8,
                           partials);
        // fused W = txt . [img ; oth]^T : 160 x 32 tiles of 128x128
        hipLaunchKernelGGL(gemm_expsum_mx,
                           dim3((B_SZ + B_SZ * K_SZ) / 128, B_SZ / 128), dim3(256),
                           0, stream, txt_f8, img_f8, oth_f8, rs1, cs1, rs2);
        hipLaunchKernelGGL(finalize_part, dim3(1), dim3(256), 0, stream,
                           rs1, cs1, rs2, partials, out);
    } else {
        hipMemsetAsync(d_ws, 0, (3 * B_SZ + 2) * sizeof(float), stream);
        hipLaunchKernelGGL((gemm_expsum<true>), dim3(B_SZ / 128, B_SZ / 128),
                           dim3(256), 0, stream, img, txt, rs1, cs1);
        hipLaunchKernelGGL((gemm_expsum<false>),
                           dim3(B_SZ * K_SZ / 128, B_SZ / 128), dim3(256), 0,
                           stream, txt, other, rs2, nullptr);
        hipLaunchKernelGGL(diag_kernel, dim3((B_SZ + B_SZ * K_SZ) / 4),
                           dim3(256), 0, stream, img, txt, other, dm);
        hipLaunchKernelGGL(finalize_atomic, dim3(1), dim3(256), 0, stream,
                           rs1, cs1, rs2, dm, out);
    }
}

// Round 6
// 652.992 us; speedup vs baseline: 1.2732x; 1.0431x over previous
//
#include <hip/hip_runtime.h>
#include <stdint.h>

#define B_SZ 4096
#define K_SZ 4
#define D_SZ 1024
#define INV_T 14.285714285714286f   // 1/0.07
#define FP8_SCALE 16.0f             // input pre-scale; compensated by E8M0=123
#define E8M0_S 123                  // 2^(123-127) = 1/16 per operand

typedef __attribute__((ext_vector_type(8)))  int   i32x8_t;   // 32 fp8 bytes
typedef __attribute__((ext_vector_type(16))) float f32x16_t;  // 32x32 acc
typedef __attribute__((ext_vector_type(8)))  short bf16x8_t;
typedef __attribute__((ext_vector_type(4)))  float f32x4_t;
typedef unsigned short u16;

static __device__ __forceinline__ u16 f2bf(float f) {
    union { float f; uint32_t u; } v; v.f = f;
    return (u16)(v.u >> 16);
}

static __device__ __forceinline__ int pack_fp8(float4 a) {
    int p = __builtin_amdgcn_cvt_pk_fp8_f32(a.x * FP8_SCALE, a.y * FP8_SCALE, 0, false);
    return  __builtin_amdgcn_cvt_pk_fp8_f32(a.z * FP8_SCALE, a.w * FP8_SCALE, p, true);
}

// async global->LDS, 16 bytes/lane; dest must be wave-uniform base + lane*16
static __device__ __forceinline__ void gl_lds16(const void* g, void* l) {
    __builtin_amdgcn_global_load_lds(
        (const __attribute__((address_space(1))) void*)g,
        (__attribute__((address_space(3))) void*)l, 16, 0, 0);
}

// ---------------------------------------------------------------------------
// Swizzled fp8 workspace layout ("fragment order on disk"):
// panel P = rows 32P..32P+31; each panel = 16 chunks (64 k) x 2048 B = 32 KB.
// Within chunk c0: byte((k>>4 &1)*1024 + ((k>>5 &1)*32 + (r&31))*16 + (k&15)).
// GEMM staging slot s then reads CONTIGUOUS global base + s*16 and stores
// lane-linear to LDS, which lands exactly in MFMA fragment order.
// ---------------------------------------------------------------------------
static __device__ __forceinline__ size_t sw_addr(int r, int k) {
    return (size_t)(r >> 5) * 32768 + (size_t)((k >> 6) * 2048)
         + (((k >> 4) & 1) * 1024) + (((k >> 5) & 1) * 512)
         + ((r & 31) * 16) + (k & 15);
}

// ===========================================================================
// MAIN PATH
// ===========================================================================

// ---------------------------------------------------------------------------
// Pass 1: convert to swizzled fp8 + diagonal dots. Block b: txt row b
// (loaded once), img row b, oth rows 4b..4b+3, plus the 5 diagonal dots.
// Thread t handles k = 4t..4t+3 (one packed int per row).
// ---------------------------------------------------------------------------
__global__ __launch_bounds__(256) void convert_diag_f8(
    const float* __restrict__ img, const float* __restrict__ txt,
    const float* __restrict__ other,
    uint8_t* __restrict__ img_sw, uint8_t* __restrict__ txt_sw,
    uint8_t* __restrict__ oth_sw, float* __restrict__ partials)
{
    const int b = blockIdx.x;
    const int t = threadIdx.x;
    const int k = 4 * t;

    float4 ti = ((const float4*)(txt + (size_t)b * D_SZ))[t];
    *(int*)(txt_sw + sw_addr(b, k)) = pack_fp8(ti);

    float4 ii = ((const float4*)(img + (size_t)b * D_SZ))[t];
    *(int*)(img_sw + sw_addr(b, k)) = pack_fp8(ii);

    float d[5];
    d[0] = ii.x * ti.x + ii.y * ti.y + ii.z * ti.z + ii.w * ti.w;
#pragma unroll
    for (int kk = 0; kk < 4; kk++) {
        float4 o = ((const float4*)(other + (size_t)(4 * b + kk) * D_SZ))[t];
        *(int*)(oth_sw + sw_addr(4 * b + kk, k)) = pack_fp8(o);
        d[1 + kk] = o.x * ti.x + o.y * ti.y + o.z * ti.z + o.w * ti.w;
    }

    __shared__ float red[5][4];
    const int w = t >> 6, lane = t & 63;
#pragma unroll
    for (int i = 0; i < 5; i++) {
        float s = d[i];
#pragma unroll
        for (int dd = 1; dd < 64; dd <<= 1) s += __shfl_xor(s, dd);
        if (lane == 0) red[i][w] = s;
    }
    __syncthreads();
    if (t == 0) {
        partials[b] = (red[0][0] + red[0][1] + red[0][2] + red[0][3]) * INV_T;
#pragma unroll
        for (int kk = 0; kk < 4; kk++)
            partials[B_SZ + 4 * b + kk] =
                (red[1 + kk][0] + red[1 + kk][1] + red[1 + kk][2] + red[1 + kk][3]) * INV_T;
    }
}

// ---------------------------------------------------------------------------
// Pass 2: fused MX-fp8 GEMM+expsum over swizzled inputs. Tile 128x128,
// BK=64; 4 waves, each a 64x64 quadrant = acc[2][2] of 32x32x64 MFMAs.
// Staging: slot s = c*256+tid reads global base + (s&127)*16 within panel
// (s>>7) chunk c0 -- contiguous 2 KB bursts (coalesced), LDS dest lane-
// linear (wave-uniform-base rule holds), LDS layout = fragment order
// (SQ_LDS_BANK_CONFLICT = 0, verified rounds 4-5).
// Epilogue: n0<4096 (W = Q1^T): rowsum->cs1, colsum->rs1; else rowsum->rs2.
// ---------------------------------------------------------------------------
__global__ __launch_bounds__(256, 2) void gemm_expsum_mx(
    const uint8_t* __restrict__ txt_sw, const uint8_t* __restrict__ img_sw,
    const uint8_t* __restrict__ oth_sw,
    float* __restrict__ rs1, float* __restrict__ cs1, float* __restrict__ rs2)
{
    __shared__ uint8_t lds[16384];   // A: [0,8192), B: [8192,16384)

    const int m0  = blockIdx.y * 128;           // txt rows
    const int n0  = blockIdx.x * 128;           // 0..20479
    const bool q1 = (n0 < B_SZ);
    const uint8_t* Yb = q1 ? img_sw + (size_t)(n0 >> 5) * 32768
                           : oth_sw + (size_t)((n0 - B_SZ) >> 5) * 32768;
    const uint8_t* Xb = txt_sw + (size_t)(m0 >> 5) * 32768;

    const int tid  = threadIdx.x;
    const int lane = tid & 63;
    const int w    = tid >> 6;
    const int wm   = (w & 1) * 64;
    const int wn   = (w >> 1) * 64;
    const int l31  = lane & 31;
    const int kh   = lane >> 5;

    // staging pointers: slot s = c*256 + tid; panel p = s>>7, within = s&127
    const uint8_t* gsrc[4];
    uint8_t* ldst[4];
#pragma unroll
    for (int c = 0; c < 4; c++) {
        const int s = (c & 1) * 256 + tid;       // 0..511 within tensor
        const int p = s >> 7, within = s & 127;
        gsrc[c] = (c < 2 ? Xb : Yb) + (size_t)p * 32768 + within * 16;
        ldst[c] = lds + (c < 2 ? 0 : 8192) + (size_t)s * 16;
    }

    f32x16_t acc[2][2];
#pragma unroll
    for (int i = 0; i < 2; i++)
#pragma unroll
        for (int j = 0; j < 2; j++)
#pragma unroll
            for (int r = 0; r < 16; r++) acc[i][j][r] = 0.f;

    for (int c0 = 0; c0 < 16; c0++) {
#pragma unroll
        for (int c = 0; c < 4; c++)
            gl_lds16(gsrc[c] + c0 * 2048, ldst[c]);
        __syncthreads();

        i32x8_t af[2], bfr[2];
#pragma unroll
        for (int mt = 0; mt < 2; mt++) {
            const int pp = 2 * (w & 1) + mt;
            int4 lo = *(const int4*)(lds + pp * 2048 + lane * 16);
            int4 hi = *(const int4*)(lds + pp * 2048 + 1024 + lane * 16);
            af[mt][0] = lo.x; af[mt][1] = lo.y; af[mt][2] = lo.z; af[mt][3] = lo.w;
            af[mt][4] = hi.x; af[mt][5] = hi.y; af[mt][6] = hi.z; af[mt][7] = hi.w;
        }
#pragma unroll
        for (int nt = 0; nt < 2; nt++) {
            const int qq = 2 * (w >> 1) + nt;
            int4 lo = *(const int4*)(lds + 8192 + qq * 2048 + lane * 16);
            int4 hi = *(const int4*)(lds + 8192 + qq * 2048 + 1024 + lane * 16);
            bfr[nt][0] = lo.x; bfr[nt][1] = lo.y; bfr[nt][2] = lo.z; bfr[nt][3] = lo.w;
            bfr[nt][4] = hi.x; bfr[nt][5] = hi.y; bfr[nt][6] = hi.z; bfr[nt][7] = hi.w;
        }

#pragma unroll
        for (int mt = 0; mt < 2; mt++)
#pragma unroll
            for (int nt = 0; nt < 2; nt++)
                acc[mt][nt] = __builtin_amdgcn_mfma_scale_f32_32x32x64_f8f6f4(
                    af[mt], bfr[nt], acc[mt][nt], 0, 0, 0, E8M0_S, 0, E8M0_S);
        __syncthreads();
    }

    // Epilogue. 32x32 C/D: col = l31, row = (r&3) + 8*(r>>2) + 4*kh.
    float* rtgt = q1 ? cs1 : rs2;
    float colp[2] = {0.f, 0.f};
#pragma unroll
    for (int mt = 0; mt < 2; mt++) {
        float rowp[16];
#pragma unroll
        for (int r = 0; r < 16; r++) rowp[r] = 0.f;
#pragma unroll
        for (int nt = 0; nt < 2; nt++)
#pragma unroll
            for (int r = 0; r < 16; r++) {
                float e = __expf(acc[mt][nt][r] * INV_T);
                rowp[r] += e;
                colp[nt] += e;
            }
#pragma unroll
        for (int r = 0; r < 16; r++) {
            float v = rowp[r];
            v += __shfl_xor(v, 1);
            v += __shfl_xor(v, 2);
            v += __shfl_xor(v, 4);
            v += __shfl_xor(v, 8);
            v += __shfl_xor(v, 16);
            if (l31 == 0) {
                const int row = m0 + wm + 32 * mt + (r & 3) + 8 * (r >> 2) + 4 * kh;
                atomicAdd(&rtgt[row], v);
            }
        }
    }
    if (q1) {
#pragma unroll
        for (int nt = 0; nt < 2; nt++) {
            float c = colp[nt];
            c += __shfl_xor(c, 32);
            if (lane < 32)
                atomicAdd(&rs1[n0 + wn + 32 * nt + l31], c);
        }
    }
}

// ---------------------------------------------------------------------------
// Finalize: logs of expsums + 20480 diagonal partials.
// ---------------------------------------------------------------------------
__global__ __launch_bounds__(256) void finalize_part(
    const float* __restrict__ rs1, const float* __restrict__ cs1,
    const float* __restrict__ rs2, const float* __restrict__ partials,
    float* __restrict__ out)
{
    float s1 = 0.f, s2 = 0.f, s3 = 0.f, pd = 0.f, pm = 0.f;
    for (int i = threadIdx.x; i < B_SZ; i += 256) {
        s1 += __logf(rs1[i]);
        s2 += __logf(cs1[i]);
        s3 += __logf(rs2[i]);
        pd += partials[i];
    }
    for (int i = threadIdx.x; i < B_SZ * K_SZ; i += 256)
        pm += partials[B_SZ + i];
#pragma unroll
    for (int d = 1; d < 64; d <<= 1) {
        s1 += __shfl_xor(s1, d); s2 += __shfl_xor(s2, d);
        s3 += __shfl_xor(s3, d); pd += __shfl_xor(pd, d);
        pm += __shfl_xor(pm, d);
    }
    __shared__ float red[5][4];
    const int w = threadIdx.x >> 6, lane = threadIdx.x & 63;
    if (lane == 0) {
        red[0][w] = s1; red[1][w] = s2; red[2][w] = s3;
        red[3][w] = pd; red[4][w] = pm;
    }
    __syncthreads();
    if (threadIdx.x == 0) {
        float S1 = red[0][0] + red[0][1] + red[0][2] + red[0][3];
        float S2 = red[1][0] + red[1][1] + red[1][2] + red[1][3];
        float S3 = red[2][0] + red[2][1] + red[2][2] + red[2][3];
        float DS = red[3][0] + red[3][1] + red[3][2] + red[3][3];
        float MS = red[4][0] + red[4][1] + red[4][2] + red[4][3];
        const float invB = 1.0f / (float)B_SZ;
        out[0] = 0.5f * (S1 + S2) * invB - DS * invB
               + 0.5f * (S3 * invB - MS / ((float)B_SZ * K_SZ));
    }
}

// ===========================================================================
// FALLBACK PATH (fp32->bf16 in-kernel, no workspace) ------------------------
// ===========================================================================
template <bool COLSUM>
__global__ __launch_bounds__(256) void gemm_expsum(
    const float* __restrict__ X, const float* __restrict__ Y,
    float* __restrict__ rowsum, float* __restrict__ colsum)
{
    __shared__ u16 As[128][32];
    __shared__ u16 Bs[128][32];
    const int m0 = blockIdx.y * 128, n0 = blockIdx.x * 128;
    const int tid = threadIdx.x, lane = tid & 63, w = tid >> 6;
    const int wm = (w & 1) * 64, wn = (w >> 1) * 64;
    const int lr = lane & 15, q = lane >> 4;
    f32x4_t acc[4][4];
#pragma unroll
    for (int i = 0; i < 4; i++)
#pragma unroll
        for (int j = 0; j < 4; j++) acc[i][j] = (f32x4_t){0.f, 0.f, 0.f, 0.f};
    const int kv = (tid & 7) * 4, r0 = tid >> 3;
    const float* xb = X + (size_t)(m0 + r0) * D_SZ + kv;
    const float* yb = Y + (size_t)(n0 + r0) * D_SZ + kv;
    for (int k0 = 0; k0 < D_SZ; k0 += 32) {
#pragma unroll
        for (int i = 0; i < 4; i++) {
            float4 a = *(const float4*)(xb + (size_t)(32 * i) * D_SZ + k0);
            float4 b = *(const float4*)(yb + (size_t)(32 * i) * D_SZ + k0);
            ushort4 ua, ub;
            ua.x = f2bf(a.x); ua.y = f2bf(a.y); ua.z = f2bf(a.z); ua.w = f2bf(a.w);
            ub.x = f2bf(b.x); ub.y = f2bf(b.y); ub.z = f2bf(b.z); ub.w = f2bf(b.w);
            *(ushort4*)&As[r0 + 32 * i][kv] = ua;
            *(ushort4*)&Bs[r0 + 32 * i][kv] = ub;
        }
        __syncthreads();
        bf16x8_t af[4], bfr[4];
#pragma unroll
        for (int mt = 0; mt < 4; mt++)
            af[mt] = *(const bf16x8_t*)&As[wm + 16 * mt + lr][8 * q];
#pragma unroll
        for (int nt = 0; nt < 4; nt++)
            bfr[nt] = *(const bf16x8_t*)&Bs[wn + 16 * nt + lr][8 * q];
#pragma unroll
        for (int mt = 0; mt < 4; mt++)
#pragma unroll
            for (int nt = 0; nt < 4; nt++)
                acc[mt][nt] = __builtin_amdgcn_mfma_f32_16x16x32_bf16(
                    af[mt], bfr[nt], acc[mt][nt], 0, 0, 0);
        __syncthreads();
    }
    float rowp[4][4];
#pragma unroll
    for (int mt = 0; mt < 4; mt++)
#pragma unroll
        for (int r = 0; r < 4; r++) rowp[mt][r] = 0.f;
#pragma unroll
    for (int nt = 0; nt < 4; nt++) {
        float colp = 0.f;
#pragma unroll
        for (int mt = 0; mt < 4; mt++)
#pragma unroll
            for (int r = 0; r < 4; r++) {
                float e = __expf(acc[mt][nt][r] * INV_T);
                colp += e; rowp[mt][r] += e;
            }
        if (COLSUM) {
            colp += __shfl_xor(colp, 16);
            colp += __shfl_xor(colp, 32);
            if (q == 0) atomicAdd(&colsum[n0 + wn + 16 * nt + lr], colp);
        }
    }
#pragma unroll
    for (int mt = 0; mt < 4; mt++)
#pragma unroll
        for (int r = 0; r < 4; r++) {
            float rp = rowp[mt][r];
            rp += __shfl_xor(rp, 1); rp += __shfl_xor(rp, 2);
            rp += __shfl_xor(rp, 4); rp += __shfl_xor(rp, 8);
            if (lr == 0) atomicAdd(&rowsum[m0 + wm + 16 * mt + 4 * q + r], rp);
        }
}

__global__ __launch_bounds__(256) void diag_kernel(
    const float* __restrict__ img, const float* __restrict__ txt,
    const float* __restrict__ other, float* __restrict__ dm)
{
    const int gw = blockIdx.x * 4 + (threadIdx.x >> 6);
    const int lane = threadIdx.x & 63;
    const float *pa, *pb; float* target;
    if (gw < B_SZ) {
        pa = img + (size_t)gw * D_SZ; pb = txt + (size_t)gw * D_SZ; target = dm;
    } else {
        const int g2 = gw - B_SZ;
        pa = other + (size_t)g2 * D_SZ; pb = txt + (size_t)(g2 >> 2) * D_SZ;
        target = dm + 1;
    }
    float s = 0.f;
#pragma unroll
    for (int j = 0; j < 4; j++) {
        float4 a = *(const float4*)(pa + 4 * (lane + 64 * j));
        float4 b = *(const float4*)(pb + 4 * (lane + 64 * j));
        s += a.x * b.x + a.y * b.y + a.z * b.z + a.w * b.w;
    }
#pragma unroll
    for (int d = 1; d < 64; d <<= 1) s += __shfl_xor(s, d);
    if (lane == 0) atomicAdd(target, s * INV_T);
}

__global__ __launch_bounds__(256) void finalize_atomic(
    const float* __restrict__ rs1, const float* __restrict__ cs1,
    const float* __restrict__ rs2, const float* __restrict__ dm,
    float* __restrict__ out)
{
    float s1 = 0.f, s2 = 0.f, s3 = 0.f;
    for (int i = threadIdx.x; i < B_SZ; i += 256) {
        s1 += __logf(rs1[i]); s2 += __logf(cs1[i]); s3 += __logf(rs2[i]);
    }
#pragma unroll
    for (int d = 1; d < 64; d <<= 1) {
        s1 += __shfl_xor(s1, d); s2 += __shfl_xor(s2, d); s3 += __shfl_xor(s3, d);
    }
    __shared__ float red[3][4];
    const int w = threadIdx.x >> 6, lane = threadIdx.x & 63;
    if (lane == 0) { red[0][w] = s1; red[1][w] = s2; red[2][w] = s3; }
    __syncthreads();
    if (threadIdx.x == 0) {
        float S1 = red[0][0] + red[0][1] + red[0][2] + red[0][3];
        float S2 = red[1][0] + red[1][1] + red[1][2] + red[1][3];
        float S3 = red[2][0] + red[2][1] + red[2][2] + red[2][3];
        const float invB = 1.0f / (float)B_SZ;
        out[0] = 0.5f * (S1 + S2) * invB - dm[0] * invB
               + 0.5f * (S3 * invB - dm[1] / ((float)B_SZ * K_SZ));
    }
}

// ===========================================================================
extern "C" void kernel_launch(void* const* d_in, const int* in_sizes, int n_in,
                              void* d_out, int out_size, void* d_ws, size_t ws_size,
                              hipStream_t stream) {
    const float* img   = (const float*)d_in[0];
    const float* txt   = (const float*)d_in[1];
    const float* other = (const float*)d_in[2];
    float* out = (float*)d_out;
    float* ws  = (float*)d_ws;

    float* rs1      = ws;                    // [4096]
    float* cs1      = ws + B_SZ;             // [4096]
    float* rs2      = ws + 2 * B_SZ;         // [4096]
    float* partials = ws + 3 * B_SZ;         // [20480] (main)
    float* dm       = ws + 3 * B_SZ;         // [2]     (fallback)

    const size_t hdr_floats = 3 * B_SZ + B_SZ + B_SZ * K_SZ;              // 32768
    const size_t f8_bytes   = (size_t)(2 * B_SZ + B_SZ * K_SZ) * D_SZ;    // 24 MB
    const size_t need = hdr_floats * sizeof(float) + f8_bytes;

    if (ws_size >= need) {
        uint8_t* txt_sw = (uint8_t*)(ws + hdr_floats);                    // 4 MB
        uint8_t* img_sw = txt_sw + (size_t)B_SZ * D_SZ;                   // 4 MB
        uint8_t* oth_sw = img_sw + (size_t)B_SZ * D_SZ;                   // 16 MB

        hipMemsetAsync(d_ws, 0, 3 * B_SZ * sizeof(float), stream);
        hipLaunchKernelGGL(convert_diag_f8, dim3(B_SZ), dim3(256),
                           0, stream, img, txt, other, img_sw, txt_sw, oth_sw,
                           partials);
        // fused W = txt . [img ; oth]^T : 160 x 32 tiles of 128x128
        hipLaunchKernelGGL(gemm_expsum_mx,
                           dim3((B_SZ + B_SZ * K_SZ) / 128, B_SZ / 128), dim3(256),
                           0, stream, txt_sw, img_sw, oth_sw, rs1, cs1, rs2);
        hipLaunchKernelGGL(finalize_part, dim3(1), dim3(256), 0, stream,
                           rs1, cs1, rs2, partials, out);
    } else {
        hipMemsetAsync(d_ws, 0, (3 * B_SZ + 2) * sizeof(float), stream);
        hipLaunchKernelGGL((gemm_expsum<true>), dim3(B_SZ / 128, B_SZ / 128),
                           dim3(256), 0, stream, img, txt, rs1, cs1);
        hipLaunchKernelGGL((gemm_expsum<false>),
                           dim3(B_SZ * K_SZ / 128, B_SZ / 128), dim3(256), 0,
                           stream, txt, other, rs2, nullptr);
        hipLaunchKernelGGL(diag_kernel, dim3((B_SZ + B_SZ * K_SZ) / 4),
                           dim3(256), 0, stream, img, txt, other, dm);
        hipLaunchKernelGGL(finalize_atomic, dim3(1), dim3(256), 0, stream,
                           rs1, cs1, rs2, dm, out);
    }
}

// Round 7
// 534.649 us; speedup vs baseline: 1.5550x; 1.2213x over previous
//
#include <hip/hip_runtime.h>
#include <stdint.h>

#define B_SZ 4096
#define K_SZ 4
#define D_SZ 1024
#define INV_T 14.285714285714286f   // 1/0.07
#define FP8_SCALE 16.0f             // input pre-scale; compensated by E8M0=123
#define E8M0_S 123                  // 2^(123-127) = 1/16 per operand

typedef __attribute__((ext_vector_type(8)))  int   i32x8_t;   // 32 fp8 bytes
typedef __attribute__((ext_vector_type(16))) float f32x16_t;  // 32x32 acc
typedef __attribute__((ext_vector_type(8)))  short bf16x8_t;
typedef __attribute__((ext_vector_type(4)))  float f32x4_t;
typedef unsigned short u16;

static __device__ __forceinline__ u16 f2bf(float f) {
    union { float f; uint32_t u; } v; v.f = f;
    return (u16)(v.u >> 16);
}

static __device__ __forceinline__ int pack_fp8(float4 a) {
    int p = __builtin_amdgcn_cvt_pk_fp8_f32(a.x * FP8_SCALE, a.y * FP8_SCALE, 0, false);
    return  __builtin_amdgcn_cvt_pk_fp8_f32(a.z * FP8_SCALE, a.w * FP8_SCALE, p, true);
}

// async global->LDS, 16 bytes/lane; dest must be wave-uniform base + lane*16
static __device__ __forceinline__ void gl_lds16(const void* g, void* l) {
    __builtin_amdgcn_global_load_lds(
        (const __attribute__((address_space(1))) void*)g,
        (__attribute__((address_space(3))) void*)l, 16, 0, 0);
}

// ---------------------------------------------------------------------------
// Swizzled fp8 workspace layout ("fragment order on disk"):
// panel P = rows 32P..32P+31; each panel = 16 chunks (64 k) x 2048 B = 32 KB.
// GEMM staging slot s then reads CONTIGUOUS global base + s*16 and stores
// lane-linear to LDS, which lands exactly in MFMA fragment order.
// ---------------------------------------------------------------------------
static __device__ __forceinline__ size_t sw_addr(int r, int k) {
    return (size_t)(r >> 5) * 32768 + (size_t)((k >> 6) * 2048)
         + (((k >> 4) & 1) * 1024) + (((k >> 5) & 1) * 512)
         + ((r & 31) * 16) + (k & 15);
}

// ===========================================================================
// MAIN PATH
// ===========================================================================

// ---------------------------------------------------------------------------
// Pass 1: convert to swizzled fp8 + diagonal dots. Block b: txt row b
// (loaded once), img row b, oth rows 4b..4b+3, plus the 5 diagonal dots.
// ---------------------------------------------------------------------------
__global__ __launch_bounds__(256) void convert_diag_f8(
    const float* __restrict__ img, const float* __restrict__ txt,
    const float* __restrict__ other,
    uint8_t* __restrict__ img_sw, uint8_t* __restrict__ txt_sw,
    uint8_t* __restrict__ oth_sw, float* __restrict__ partials)
{
    const int b = blockIdx.x;
    const int t = threadIdx.x;
    const int k = 4 * t;

    float4 ti = ((const float4*)(txt + (size_t)b * D_SZ))[t];
    *(int*)(txt_sw + sw_addr(b, k)) = pack_fp8(ti);

    float4 ii = ((const float4*)(img + (size_t)b * D_SZ))[t];
    *(int*)(img_sw + sw_addr(b, k)) = pack_fp8(ii);

    float d[5];
    d[0] = ii.x * ti.x + ii.y * ti.y + ii.z * ti.z + ii.w * ti.w;
#pragma unroll
    for (int kk = 0; kk < 4; kk++) {
        float4 o = ((const float4*)(other + (size_t)(4 * b + kk) * D_SZ))[t];
        *(int*)(oth_sw + sw_addr(4 * b + kk, k)) = pack_fp8(o);
        d[1 + kk] = o.x * ti.x + o.y * ti.y + o.z * ti.z + o.w * ti.w;
    }

    __shared__ float red[5][4];
    const int w = t >> 6, lane = t & 63;
#pragma unroll
    for (int i = 0; i < 5; i++) {
        float s = d[i];
#pragma unroll
        for (int dd = 1; dd < 64; dd <<= 1) s += __shfl_xor(s, dd);
        if (lane == 0) red[i][w] = s;
    }
    __syncthreads();
    if (t == 0) {
        partials[b] = (red[0][0] + red[0][1] + red[0][2] + red[0][3]) * INV_T;
#pragma unroll
        for (int kk = 0; kk < 4; kk++)
            partials[B_SZ + 4 * b + kk] =
                (red[1 + kk][0] + red[1 + kk][1] + red[1 + kk][2] + red[1 + kk][3]) * INV_T;
    }
}

// ---------------------------------------------------------------------------
// Pass 2: fused MX-fp8 GEMM+expsum over swizzled inputs. Tile 128x128,
// BK=64; 4 waves, each a 64x64 quadrant = acc[2][2] of 32x32x64 MFMAs.
// Round-7 changes vs round 6 (which was correct but latency-bound):
//  (a) XCD-aware 1-D block swizzle: XCD (id&7) owns by in [4*xcd,4*xcd+4);
//      inner order = 20 chunks of (8 bx x 4 by) -> per-XCD L2 working set
//      ~1.5 MB (A 512 KB + B 1 MB) << 4 MB: staging becomes L2 hits.
//  (b) double-buffered LDS (2x16 KB): stage buf^1 immediately after the
//      barrier, compute from buf -> the vmcnt(0) drain at the NEXT barrier
//      waits on loads that aged through a full ds_read+MFMA phase.
// LDS layout = fragment order (SQ_LDS_BANK_CONFLICT=0, verified r4-r6);
// staging slot s reads contiguous global base + s*16 (verified r6).
// Epilogue: n0<4096 (W = Q1^T): rowsum->cs1, colsum->rs1; else rowsum->rs2.
// ---------------------------------------------------------------------------
__global__ __launch_bounds__(256, 2) void gemm_expsum_mx(
    const uint8_t* __restrict__ txt_sw, const uint8_t* __restrict__ img_sw,
    const uint8_t* __restrict__ oth_sw,
    float* __restrict__ rs1, float* __restrict__ cs1, float* __restrict__ rs2)
{
    __shared__ uint8_t lds[2][16384];   // per buffer: A [0,8192), B [8192,16384)

    // XCD-aware swizzle of the 5120-block 1-D grid (grid = 160 bx x 32 by)
    const int g      = blockIdx.x;
    const int xcd    = g & 7;
    const int local  = g >> 3;            // 0..639
    const int chunk  = local >> 5;        // 0..19
    const int within = local & 31;
    const int bx     = chunk * 8 + (within & 7);    // 0..159
    const int by     = (xcd << 2) + (within >> 3);  // 0..31

    const int m0  = by * 128;             // txt rows
    const int n0  = bx * 128;             // 0..20479
    const bool q1 = (n0 < B_SZ);
    const uint8_t* Yb = q1 ? img_sw + (size_t)(n0 >> 5) * 32768
                           : oth_sw + (size_t)((n0 - B_SZ) >> 5) * 32768;
    const uint8_t* Xb = txt_sw + (size_t)(m0 >> 5) * 32768;

    const int tid  = threadIdx.x;
    const int lane = tid & 63;
    const int w    = tid >> 6;
    const int wm   = (w & 1) * 64;
    const int wn   = (w >> 1) * 64;
    const int l31  = lane & 31;
    const int kh   = lane >> 5;

    // staging: slot s = (c&1)*256 + tid; global = tensor panel (s>>7) + (s&127)*16
    const uint8_t* gsrc[4];
    int ldoff[4];
#pragma unroll
    for (int c = 0; c < 4; c++) {
        const int s = (c & 1) * 256 + tid;       // 0..511 within tensor
        gsrc[c]  = (c < 2 ? Xb : Yb) + (size_t)(s >> 7) * 32768 + (s & 127) * 16;
        ldoff[c] = (c < 2 ? 0 : 8192) + s * 16;
    }

    f32x16_t acc[2][2];
#pragma unroll
    for (int i = 0; i < 2; i++)
#pragma unroll
        for (int j = 0; j < 2; j++)
#pragma unroll
            for (int r = 0; r < 16; r++) acc[i][j][r] = 0.f;

    // prologue: stage chunk 0 into buffer 0
#pragma unroll
    for (int c = 0; c < 4; c++)
        gl_lds16(gsrc[c], &lds[0][0] + ldoff[c]);

    int cur = 0;
    for (int c0 = 0; c0 < 16; c0++) {
        __syncthreads();   // drains vmcnt: lds[cur] ready; all reads of lds[cur^1] done

        // prefetch next chunk into the other buffer (aged past the MFMA phase)
        if (c0 + 1 < 16) {
#pragma unroll
            for (int c = 0; c < 4; c++)
                gl_lds16(gsrc[c] + (c0 + 1) * 2048, &lds[cur ^ 1][0] + ldoff[c]);
        }

        const uint8_t* buf = &lds[cur][0];
        i32x8_t af[2], bfr[2];
#pragma unroll
        for (int mt = 0; mt < 2; mt++) {
            const int pp = 2 * (w & 1) + mt;
            int4 lo = *(const int4*)(buf + pp * 2048 + lane * 16);
            int4 hi = *(const int4*)(buf + pp * 2048 + 1024 + lane * 16);
            af[mt][0] = lo.x; af[mt][1] = lo.y; af[mt][2] = lo.z; af[mt][3] = lo.w;
            af[mt][4] = hi.x; af[mt][5] = hi.y; af[mt][6] = hi.z; af[mt][7] = hi.w;
        }
#pragma unroll
        for (int nt = 0; nt < 2; nt++) {
            const int qq = 2 * (w >> 1) + nt;
            int4 lo = *(const int4*)(buf + 8192 + qq * 2048 + lane * 16);
            int4 hi = *(const int4*)(buf + 8192 + qq * 2048 + 1024 + lane * 16);
            bfr[nt][0] = lo.x; bfr[nt][1] = lo.y; bfr[nt][2] = lo.z; bfr[nt][3] = lo.w;
            bfr[nt][4] = hi.x; bfr[nt][5] = hi.y; bfr[nt][6] = hi.z; bfr[nt][7] = hi.w;
        }

#pragma unroll
        for (int mt = 0; mt < 2; mt++)
#pragma unroll
            for (int nt = 0; nt < 2; nt++)
                acc[mt][nt] = __builtin_amdgcn_mfma_scale_f32_32x32x64_f8f6f4(
                    af[mt], bfr[nt], acc[mt][nt], 0, 0, 0, E8M0_S, 0, E8M0_S);
        cur ^= 1;
    }

    // Epilogue. 32x32 C/D: col = l31, row = (r&3) + 8*(r>>2) + 4*kh.
    float* rtgt = q1 ? cs1 : rs2;
    float colp[2] = {0.f, 0.f};
#pragma unroll
    for (int mt = 0; mt < 2; mt++) {
        float rowp[16];
#pragma unroll
        for (int r = 0; r < 16; r++) rowp[r] = 0.f;
#pragma unroll
        for (int nt = 0; nt < 2; nt++)
#pragma unroll
            for (int r = 0; r < 16; r++) {
                float e = __expf(acc[mt][nt][r] * INV_T);
                rowp[r] += e;
                colp[nt] += e;
            }
#pragma unroll
        for (int r = 0; r < 16; r++) {
            float v = rowp[r];
            v += __shfl_xor(v, 1);
            v += __shfl_xor(v, 2);
            v += __shfl_xor(v, 4);
            v += __shfl_xor(v, 8);
            v += __shfl_xor(v, 16);
            if (l31 == 0) {
                const int row = m0 + wm + 32 * mt + (r & 3) + 8 * (r >> 2) + 4 * kh;
                atomicAdd(&rtgt[row], v);
            }
        }
    }
    if (q1) {
#pragma unroll
        for (int nt = 0; nt < 2; nt++) {
            float c = colp[nt];
            c += __shfl_xor(c, 32);
            if (lane < 32)
                atomicAdd(&rs1[n0 + wn + 32 * nt + l31], c);
        }
    }
}

// ---------------------------------------------------------------------------
// Finalize: logs of expsums + 20480 diagonal partials.
// ---------------------------------------------------------------------------
__global__ __launch_bounds__(256) void finalize_part(
    const float* __restrict__ rs1, const float* __restrict__ cs1,
    const float* __restrict__ rs2, const float* __restrict__ partials,
    float* __restrict__ out)
{
    float s1 = 0.f, s2 = 0.f, s3 = 0.f, pd = 0.f, pm = 0.f;
    for (int i = threadIdx.x; i < B_SZ; i += 256) {
        s1 += __logf(rs1[i]);
        s2 += __logf(cs1[i]);
        s3 += __logf(rs2[i]);
        pd += partials[i];
    }
    for (int i = threadIdx.x; i < B_SZ * K_SZ; i += 256)
        pm += partials[B_SZ + i];
#pragma unroll
    for (int d = 1; d < 64; d <<= 1) {
        s1 += __shfl_xor(s1, d); s2 += __shfl_xor(s2, d);
        s3 += __shfl_xor(s3, d); pd += __shfl_xor(pd, d);
        pm += __shfl_xor(pm, d);
    }
    __shared__ float red[5][4];
    const int w = threadIdx.x >> 6, lane = threadIdx.x & 63;
    if (lane == 0) {
        red[0][w] = s1; red[1][w] = s2; red[2][w] = s3;
        red[3][w] = pd; red[4][w] = pm;
    }
    __syncthreads();
    if (threadIdx.x == 0) {
        float S1 = red[0][0] + red[0][1] + red[0][2] + red[0][3];
        float S2 = red[1][0] + red[1][1] + red[1][2] + red[1][3];
        float S3 = red[2][0] + red[2][1] + red[2][2] + red[2][3];
        float DS = red[3][0] + red[3][1] + red[3][2] + red[3][3];
        float MS = red[4][0] + red[4][1] + red[4][2] + red[4][3];
        const float invB = 1.0f / (float)B_SZ;
        out[0] = 0.5f * (S1 + S2) * invB - DS * invB
               + 0.5f * (S3 * invB - MS / ((float)B_SZ * K_SZ));
    }
}

// ===========================================================================
// FALLBACK PATH (fp32->bf16 in-kernel, no workspace) ------------------------
// ===========================================================================
template <bool COLSUM>
__global__ __launch_bounds__(256) void gemm_expsum(
    const float* __restrict__ X, const float* __restrict__ Y,
    float* __restrict__ rowsum, float* __restrict__ colsum)
{
    __shared__ u16 As[128][32];
    __shared__ u16 Bs[128][32];
    const int m0 = blockIdx.y * 128, n0 = blockIdx.x * 128;
    const int tid = threadIdx.x, lane = tid & 63, w = tid >> 6;
    const int wm = (w & 1) * 64, wn = (w >> 1) * 64;
    const int lr = lane & 15, q = lane >> 4;
    f32x4_t acc[4][4];
#pragma unroll
    for (int i = 0; i < 4; i++)
#pragma unroll
        for (int j = 0; j < 4; j++) acc[i][j] = (f32x4_t){0.f, 0.f, 0.f, 0.f};
    const int kv = (tid & 7) * 4, r0 = tid >> 3;
    const float* xb = X + (size_t)(m0 + r0) * D_SZ + kv;
    const float* yb = Y + (size_t)(n0 + r0) * D_SZ + kv;
    for (int k0 = 0; k0 < D_SZ; k0 += 32) {
#pragma unroll
        for (int i = 0; i < 4; i++) {
            float4 a = *(const float4*)(xb + (size_t)(32 * i) * D_SZ + k0);
            float4 b = *(const float4*)(yb + (size_t)(32 * i) * D_SZ + k0);
            ushort4 ua, ub;
            ua.x = f2bf(a.x); ua.y = f2bf(a.y); ua.z = f2bf(a.z); ua.w = f2bf(a.w);
            ub.x = f2bf(b.x); ub.y = f2bf(b.y); ub.z = f2bf(b.z); ub.w = f2bf(b.w);
            *(ushort4*)&As[r0 + 32 * i][kv] = ua;
            *(ushort4*)&Bs[r0 + 32 * i][kv] = ub;
        }
        __syncthreads();
        bf16x8_t af[4], bfr[4];
#pragma unroll
        for (int mt = 0; mt < 4; mt++)
            af[mt] = *(const bf16x8_t*)&As[wm + 16 * mt + lr][8 * q];
#pragma unroll
        for (int nt = 0; nt < 4; nt++)
            bfr[nt] = *(const bf16x8_t*)&Bs[wn + 16 * nt + lr][8 * q];
#pragma unroll
        for (int mt = 0; mt < 4; mt++)
#pragma unroll
            for (int nt = 0; nt < 4; nt++)
                acc[mt][nt] = __builtin_amdgcn_mfma_f32_16x16x32_bf16(
                    af[mt], bfr[nt], acc[mt][nt], 0, 0, 0);
        __syncthreads();
    }
    float rowp[4][4];
#pragma unroll
    for (int mt = 0; mt < 4; mt++)
#pragma unroll
        for (int r = 0; r < 4; r++) rowp[mt][r] = 0.f;
#pragma unroll
    for (int nt = 0; nt < 4; nt++) {
        float colp = 0.f;
#pragma unroll
        for (int mt = 0; mt < 4; mt++)
#pragma unroll
            for (int r = 0; r < 4; r++) {
                float e = __expf(acc[mt][nt][r] * INV_T);
                colp += e; rowp[mt][r] += e;
            }
        if (COLSUM) {
            colp += __shfl_xor(colp, 16);
            colp += __shfl_xor(colp, 32);
            if (q == 0) atomicAdd(&colsum[n0 + wn + 16 * nt + lr], colp);
        }
    }
#pragma unroll
    for (int mt = 0; mt < 4; mt++)
#pragma unroll
        for (int r = 0; r < 4; r++) {
            float rp = rowp[mt][r];
            rp += __shfl_xor(rp, 1); rp += __shfl_xor(rp, 2);
            rp += __shfl_xor(rp, 4); rp += __shfl_xor(rp, 8);
            if (lr == 0) atomicAdd(&rowsum[m0 + wm + 16 * mt + 4 * q + r], rp);
        }
}

__global__ __launch_bounds__(256) void diag_kernel(
    const float* __restrict__ img, const float* __restrict__ txt,
    const float* __restrict__ other, float* __restrict__ dm)
{
    const int gw = blockIdx.x * 4 + (threadIdx.x >> 6);
    const int lane = threadIdx.x & 63;
    const float *pa, *pb; float* target;
    if (gw < B_SZ) {
        pa = img + (size_t)gw * D_SZ; pb = txt + (size_t)gw * D_SZ; target = dm;
    } else {
        const int g2 = gw - B_SZ;
        pa = other + (size_t)g2 * D_SZ; pb = txt + (size_t)(g2 >> 2) * D_SZ;
        target = dm + 1;
    }
    float s = 0.f;
#pragma unroll
    for (int j = 0; j < 4; j++) {
        float4 a = *(const float4*)(pa + 4 * (lane + 64 * j));
        float4 b = *(const float4*)(pb + 4 * (lane + 64 * j));
        s += a.x * b.x + a.y * b.y + a.z * b.z + a.w * b.w;
    }
#pragma unroll
    for (int d = 1; d < 64; d <<= 1) s += __shfl_xor(s, d);
    if (lane == 0) atomicAdd(target, s * INV_T);
}

__global__ __launch_bounds__(256) void finalize_atomic(
    const float* __restrict__ rs1, const float* __restrict__ cs1,
    const float* __restrict__ rs2, const float* __restrict__ dm,
    float* __restrict__ out)
{
    float s1 = 0.f, s2 = 0.f, s3 = 0.f;
    for (int i = threadIdx.x; i < B_SZ; i += 256) {
        s1 += __logf(rs1[i]); s2 += __logf(cs1[i]); s3 += __logf(rs2[i]);
    }
#pragma unroll
    for (int d = 1; d < 64; d <<= 1) {
        s1 += __shfl_xor(s1, d); s2 += __shfl_xor(s2, d); s3 += __shfl_xor(s3, d);
    }
    __shared__ float red[3][4];
    const int w = threadIdx.x >> 6, lane = threadIdx.x & 63;
    if (lane == 0) { red[0][w] = s1; red[1][w] = s2; red[2][w] = s3; }
    __syncthreads();
    if (threadIdx.x == 0) {
        float S1 = red[0][0] + red[0][1] + red[0][2] + red[0][3];
        float S2 = red[1][0] + red[1][1] + red[1][2] + red[1][3];
        float S3 = red[2][0] + red[2][1] + red[2][2] + red[2][3];
        const float invB = 1.0f / (float)B_SZ;
        out[0] = 0.5f * (S1 + S2) * invB - dm[0] * invB
               + 0.5f * (S3 * invB - dm[1] / ((float)B_SZ * K_SZ));
    }
}

// ===========================================================================
extern "C" void kernel_launch(void* const* d_in, const int* in_sizes, int n_in,
                              void* d_out, int out_size, void* d_ws, size_t ws_size,
                              hipStream_t stream) {
    const float* img   = (const float*)d_in[0];
    const float* txt   = (const float*)d_in[1];
    const float* other = (const float*)d_in[2];
    float* out = (float*)d_out;
    float* ws  = (float*)d_ws;

    float* rs1      = ws;                    // [4096]
    float* cs1      = ws + B_SZ;             // [4096]
    float* rs2      = ws + 2 * B_SZ;         // [4096]
    float* partials = ws + 3 * B_SZ;         // [20480] (main)
    float* dm       = ws + 3 * B_SZ;         // [2]     (fallback)

    const size_t hdr_floats = 3 * B_SZ + B_SZ + B_SZ * K_SZ;              // 32768
    const size_t f8_bytes   = (size_t)(2 * B_SZ + B_SZ * K_SZ) * D_SZ;    // 24 MB
    const size_t need = hdr_floats * sizeof(float) + f8_bytes;

    if (ws_size >= need) {
        uint8_t* txt_sw = (uint8_t*)(ws + hdr_floats);                    // 4 MB
        uint8_t* img_sw = txt_sw + (size_t)B_SZ * D_SZ;                   // 4 MB
        uint8_t* oth_sw = img_sw + (size_t)B_SZ * D_SZ;                   // 16 MB

        hipMemsetAsync(d_ws, 0, 3 * B_SZ * sizeof(float), stream);
        hipLaunchKernelGGL(convert_diag_f8, dim3(B_SZ), dim3(256),
                           0, stream, img, txt, other, img_sw, txt_sw, oth_sw,
                           partials);
        // fused W = txt . [img ; oth]^T : 5120 blocks, XCD-swizzled 1-D grid
        hipLaunchKernelGGL(gemm_expsum_mx, dim3(5120), dim3(256),
                           0, stream, txt_sw, img_sw, oth_sw, rs1, cs1, rs2);
        hipLaunchKernelGGL(finalize_part, dim3(1), dim3(256), 0, stream,
                           rs1, cs1, rs2, partials, out);
    } else {
        hipMemsetAsync(d_ws, 0, (3 * B_SZ + 2) * sizeof(float), stream);
        hipLaunchKernelGGL((gemm_expsum<true>), dim3(B_SZ / 128, B_SZ / 128),
                           dim3(256), 0, stream, img, txt, rs1, cs1);
        hipLaunchKernelGGL((gemm_expsum<false>),
                           dim3(B_SZ * K_SZ / 128, B_SZ / 128), dim3(256), 0,
                           stream, txt, other, rs2, nullptr);
        hipLaunchKernelGGL(diag_kernel, dim3((B_SZ + B_SZ * K_SZ) / 4),
                           dim3(256), 0, stream, img, txt, other, dm);
        hipLaunchKernelGGL(finalize_atomic, dim3(1), dim3(256), 0, stream,
                           rs1, cs1, rs2, dm, out);
    }
}